// Round 7
// baseline (168.781 us; speedup 1.0000x reference)
//
#include <hip/hip_runtime.h>
#include <stdint.h>

#define SEQ 8192
#define DIN 768
#define DOUT 128

typedef __attribute__((ext_vector_type(8))) short short8;
typedef __attribute__((ext_vector_type(8))) unsigned short ushort8v;
typedef __attribute__((ext_vector_type(4))) float f32x4;

// softmax exp base conversion: (1/sqrt(128)) * log2(e), folded into wq/x at convert
#define CEXPF (1.4426950408889634f * 0.08838834764831845f)

#if __has_builtin(__builtin_amdgcn_exp2f)
#define EXP2(x) __builtin_amdgcn_exp2f(x)
#else
#define EXP2(x) __builtin_exp2f(x)
#endif

// round-half-up f32->bf16 (2 VALU ops)
__device__ __forceinline__ unsigned short f2bf(float f) {
  return (unsigned short)((__float_as_uint(f) + 0x8000u) >> 16);
}

// async global->LDS DMA, 16B per lane; consecutive lanes -> consecutive 16B.
__device__ __forceinline__ void gload_lds16(const void* g, void* l) {
  __builtin_amdgcn_global_load_lds(
      (const __attribute__((address_space(1))) void*)g,
      (__attribute__((address_space(3))) void*)l, 16, 0, 0);
}

// ---------------------------------------------------------------------------
// Kernel 0: fp32 -> bf16 convert of x AND the three W's (wq scaled by CEXPF).
// (R4 version — known good.)
// ---------------------------------------------------------------------------
#define XELEMS (SEQ * DIN)          // 6291456
#define WELEMS (DOUT * DIN)         // 98304
__global__ void conv_kernel(const float* __restrict__ x,
                            const float* __restrict__ wq,
                            const float* __restrict__ wk,
                            const float* __restrict__ wv,
                            unsigned short* __restrict__ xb,
                            unsigned short* __restrict__ Wb) {
  int idx4 = (blockIdx.x * 256 + threadIdx.x) * 4;
  const float* src;
  unsigned short* dst;
  float sc = 1.0f;
  if (idx4 < XELEMS) {
    src = x + idx4;
    dst = xb + idx4;
  } else {
    int wi = idx4 - XELEMS;
    int z  = wi / WELEMS;
    int rem = wi - z * WELEMS;
    src = ((z == 0) ? wq : (z == 1) ? wk : wv) + rem;
    dst = Wb + wi;
    if (z == 0) sc = CEXPF;
  }
  float4 v = *(const float4*)src;
  ushort4 o;
  o.x = f2bf(v.x * sc); o.y = f2bf(v.y * sc);
  o.z = f2bf(v.z * sc); o.w = f2bf(v.w * sc);
  *(ushort4*)dst = o;
}

// ---------------------------------------------------------------------------
// Kernel A: QKV projection, m97-style bf16 GEMM (R4 version — known good).
// ---------------------------------------------------------------------------
__launch_bounds__(256, 2)
__global__ void qkv_kernel(const unsigned short* __restrict__ xb,
                           const unsigned short* __restrict__ Wb,
                           unsigned short* __restrict__ Qb,
                           unsigned short* __restrict__ Kb,
                           unsigned short* __restrict__ Vtb) {
  __shared__ unsigned char lds_u[35072];
  unsigned char* xs = lds_u;            // [128 seqrow][64 k] bf16, 8 chunks XOR-swz
  unsigned char* ws = lds_u + 16384;    // [128 outcol][64 k]

  const int t    = threadIdx.x;
  const int w    = t >> 6;
  const int lane = t & 63;
  const int g    = lane >> 4;
  const int r    = lane & 15;
  const int z    = blockIdx.y;
  const int m0   = blockIdx.x * 128;
  const unsigned short* Wz = Wb + (size_t)z * WELEMS;

  f32x4 acc[2][8];
#pragma unroll
  for (int i = 0; i < 2; i++)
#pragma unroll
    for (int j = 0; j < 8; j++) acc[i][j] = 0.f;

#pragma unroll 1
  for (int kb = 0; kb < DIN; kb += 64) {
#pragma unroll
    for (int c = 0; c < 4; c++) {
      int ci = (w * 4 + c) * 64 + lane;
      int row = ci >> 3, ch = ci & 7;
      int sch = ch ^ (row & 7);
      gload_lds16(xb + (size_t)(m0 + row) * DIN + kb + sch * 8,
                  xs + ((w * 4 + c) << 10) + (lane << 4));
      gload_lds16(Wz + (size_t)row * DIN + kb + sch * 8,
                  ws + ((w * 4 + c) << 10) + (lane << 4));
    }
    __syncthreads();

    short8 af[2][2], bf[2];
#pragma unroll
    for (int mt = 0; mt < 2; mt++)
#pragma unroll
      for (int kc = 0; kc < 2; kc++) {
        int row = w * 32 + mt * 16 + r;
        af[mt][kc] = *(const short8*)(ws + row * 128 + (((kc * 4 + g) ^ (r & 7)) << 4));
      }
#pragma unroll
    for (int nt = 0; nt < 8; nt++) {
      int row = nt * 16 + r;
#pragma unroll
      for (int kc = 0; kc < 2; kc++)
        bf[kc] = *(const short8*)(xs + row * 128 + (((kc * 4 + g) ^ (r & 7)) << 4));
#pragma unroll
      for (int mt = 0; mt < 2; mt++) {
        acc[mt][nt] = __builtin_amdgcn_mfma_f32_16x16x32_bf16(af[mt][0], bf[0], acc[mt][nt], 0, 0, 0);
        acc[mt][nt] = __builtin_amdgcn_mfma_f32_16x16x32_bf16(af[mt][1], bf[1], acc[mt][nt], 0, 0, 0);
      }
    }
    __syncthreads();
  }

  if (z < 2) {
    unsigned short* out = (z == 0) ? Qb : Kb;
#pragma unroll
    for (int mt = 0; mt < 2; mt++)
#pragma unroll
      for (int nt = 0; nt < 8; nt++) {
        ushort4 o;
        o.x = f2bf(acc[mt][nt][0]); o.y = f2bf(acc[mt][nt][1]);
        o.z = f2bf(acc[mt][nt][2]); o.w = f2bf(acc[mt][nt][3]);
        *(ushort4*)(out + (size_t)(m0 + nt * 16 + r) * DOUT + w * 32 + mt * 16 + g * 4) = o;
      }
  } else {
    unsigned short* ct = (unsigned short*)lds_u;   // [128 seqrow][136]
#pragma unroll
    for (int mt = 0; mt < 2; mt++)
#pragma unroll
      for (int nt = 0; nt < 8; nt++) {
        ushort4 o;
        o.x = f2bf(acc[mt][nt][0]); o.y = f2bf(acc[mt][nt][1]);
        o.z = f2bf(acc[mt][nt][2]); o.w = f2bf(acc[mt][nt][3]);
        *(ushort4*)&ct[(nt * 16 + r) * 136 + w * 32 + mt * 16 + g * 4] = o;
      }
    __syncthreads();
    int col  = t >> 1;
    int half = (t & 1) * 64;
#pragma unroll
    for (int h = 0; h < 8; h++) {
      ushort8v a;
#pragma unroll
      for (int i = 0; i < 8; i++) a[i] = ct[(half + h * 8 + i) * 136 + col];
      *(ushort8v*)(Vtb + (size_t)col * SEQ + m0 + half + h * 8) = a;
    }
  }
}

// ---------------------------------------------------------------------------
// Kernel B: flash attention v3.  grid (8 splits, 64 qblocks) — blockIdx.x=sp
// so each XCD hosts one KV-split (L2-resident 256KB K + 256KB V slice).
// block 256 = 4 waves x 32 q.  BN=64.  K-frags read DIRECTLY from global (L2);
// only V is staged in LDS (double-buffered, 1 barrier/iter).  P stays in
// registers: S^T C-layout == PV B-frag layout under virtual-k relabeling.
// ---------------------------------------------------------------------------
__launch_bounds__(256, 2)
__global__ void attn_kernel(const unsigned short* __restrict__ Qb,
                            const unsigned short* __restrict__ Kb,
                            const unsigned short* __restrict__ Vtb,
                            float* __restrict__ Opart,
                            float* __restrict__ lpart) {
  // Vl[buf][d=0..127][8 x 16B chunks], 16B chunk p16 = c16 ^ ((d>>1)&7)
  __shared__ unsigned char Vl[2][16384];

  const int t    = threadIdx.x;
  const int wave = t >> 6;
  const int lane = t & 63;
  const int g    = lane >> 4;
  const int r    = lane & 15;

  const int sp = blockIdx.x;
  const int qb = blockIdx.y;
  const int q0 = qb * 128 + wave * 32;

  // Q B-frags (pre-scaled by CEXPF): n=q=r, k=kc*32+g*8+j
  short8 qf[2][4];
#pragma unroll
  for (int nt = 0; nt < 2; nt++)
#pragma unroll
    for (int kc = 0; kc < 4; kc++)
      qf[nt][kc] = *(const short8*)(Qb + (size_t)(q0 + nt * 16 + r) * DOUT + kc * 32 + g * 8);

  // all-ones A-frag for the l row-sum MFMA
  short8 onesf;
#pragma unroll
  for (int j = 0; j < 8; j++) onesf[j] = (short)0x3F80;

  f32x4 oacc[2][8];   // D[m=d local][n=q]: [nt][dg]
  f32x4 lacc[2];
#pragma unroll
  for (int nt = 0; nt < 2; nt++) {
    lacc[nt] = 0.f;
#pragma unroll
    for (int dg = 0; dg < 8; dg++) oacc[nt][dg] = 0.f;
  }

#pragma unroll 1
  for (int it = 0; it < 16; it++) {
    const int kv0 = sp * 1024 + it * 64;
    unsigned char* Vb = Vl[it & 1];

    // ---- K A-frags from global (L2-hot): A[m=kv local][k], 16 x b128 ----
    short8 kf[4][4];
#pragma unroll
    for (int mt = 0; mt < 4; mt++)
#pragma unroll
      for (int kc = 0; kc < 4; kc++)
        kf[mt][kc] = *(const short8*)(Kb + (size_t)(kv0 + mt * 16 + r) * DOUT + kc * 32 + g * 8);

    // ---- V DMA into buf (issued after kf loads: vmcnt lets S^T proceed) ----
#pragma unroll
    for (int c = 0; c < 4; c++) {
      int idx = (wave * 4 + c) * 64 + lane;     // 0..1023
      int d = idx >> 3, p16 = idx & 7;
      int c16 = p16 ^ ((d >> 1) & 7);
      gload_lds16(Vtb + (size_t)d * SEQ + kv0 + c16 * 8,
                  Vb + ((wave * 4 + c) << 10) + (lane << 4));
    }

    // ---- S^T = K Q^T : sf[mt][nt], lane holds kv=mt*16+g*4+rr, q=r ----
    f32x4 sf[4][2];
#pragma unroll
    for (int mt = 0; mt < 4; mt++)
#pragma unroll
      for (int nt = 0; nt < 2; nt++) sf[mt][nt] = 0.f;
#pragma unroll
    for (int mt = 0; mt < 4; mt++)
#pragma unroll
      for (int kc = 0; kc < 4; kc++) {
        sf[mt][0] = __builtin_amdgcn_mfma_f32_16x16x32_bf16(kf[mt][kc], qf[0][kc], sf[mt][0], 0, 0, 0);
        sf[mt][1] = __builtin_amdgcn_mfma_f32_16x16x32_bf16(kf[mt][kc], qf[1][kc], sf[mt][1], 0, 0, 0);
      }

    // ---- p = exp2(s), packed DIRECTLY into PV B-frags (no LDS round-trip).
    // Virtual k for pair h: j0..3 <- kv (2h)*16+g*4+j, j4..7 <- kv (2h+1)*16+g*4+j
    short8 pf[2][2];   // [h][nt]
#pragma unroll
    for (int h = 0; h < 2; h++)
#pragma unroll
      for (int nt = 0; nt < 2; nt++) {
        ushort8v p;
#pragma unroll
        for (int j = 0; j < 4; j++) {
          p[j]     = f2bf(EXP2(sf[2 * h][nt][j]));
          p[j + 4] = f2bf(EXP2(sf[2 * h + 1][nt][j]));
        }
        pf[h][nt] = (short8)p;
      }

    __syncthreads();   // V DMA visible; also separates PV(i-?) from DMA overwrite

    // ---- O += P V : A = V frags (paired b64 reads matching virtual k) ----
#pragma unroll
    for (int dg = 0; dg < 8; dg++) {
      int d = dg * 16 + r;
      const unsigned char* vrow = Vb + d * 128;
      int sw = (r >> 1) & 7;                     // ^((d>>1)&7) with d=dg*16+r
      int hb = (g & 1) * 8;
#pragma unroll
      for (int h = 0; h < 2; h++) {
        int p16a = (4 * h + (g >> 1)) ^ sw;      // chunk for kv (2h)*16+g*4
        // second half: s_b = s_a + 4  ->  p16b = p16a ^ 2
        union { uint2 u2[2]; short8 s8; } vv;
        vv.u2[0] = *(const uint2*)(vrow + p16a * 16 + hb);
        vv.u2[1] = *(const uint2*)(vrow + (p16a ^ 2) * 16 + hb);
        short8 vf = vv.s8;
#pragma unroll
        for (int nt = 0; nt < 2; nt++)
          oacc[nt][dg] = __builtin_amdgcn_mfma_f32_16x16x32_bf16(vf, pf[h][nt], oacc[nt][dg], 0, 0, 0);
      }
    }
    // ---- l += ones^T P ----
#pragma unroll
    for (int nt = 0; nt < 2; nt++) {
      lacc[nt] = __builtin_amdgcn_mfma_f32_16x16x32_bf16(onesf, pf[0][nt], lacc[nt], 0, 0, 0);
      lacc[nt] = __builtin_amdgcn_mfma_f32_16x16x32_bf16(onesf, pf[1][nt], lacc[nt], 0, 0, 0);
    }
  }

  // ---- write partials: D[m=d=g*4+rr+16dg][n=q=r] -> float4 per (nt,dg) ----
  const size_t pbase = (size_t)sp * SEQ;
#pragma unroll
  for (int nt = 0; nt < 2; nt++) {
    int q = q0 + nt * 16 + r;
    float* orow = Opart + (pbase + q) * DOUT;
#pragma unroll
    for (int dg = 0; dg < 8; dg++)
      *(f32x4*)(orow + dg * 16 + g * 4) = oacc[nt][dg];
    if (g == 0) lpart[pbase + q] = lacc[nt][0];
  }
}

// ---------------------------------------------------------------------------
// Kernel C: combine 8 KV-split partials (plain sum + normalize).
// ---------------------------------------------------------------------------
__global__ void combine_kernel(const float* __restrict__ Opart,
                               const float* __restrict__ lpart,
                               float* __restrict__ out) {
  int idx = blockIdx.x * 256 + threadIdx.x;  // 8192*32
  int s   = idx >> 5;
  int d4  = (idx & 31) * 4;
  float L = 0.f;
  f32x4 acc = 0.f;
#pragma unroll
  for (int p = 0; p < 8; p++) {
    L += lpart[p * SEQ + s];
    acc += *(const f32x4*)(Opart + ((size_t)p * SEQ + s) * DOUT + d4);
  }
  f32x4 res = acc * (1.0f / L);
  *(f32x4*)(out + (size_t)s * DOUT + d4) = res;
}

// ---------------------------------------------------------------------------
extern "C" void kernel_launch(void* const* d_in, const int* in_sizes, int n_in,
                              void* d_out, int out_size, void* d_ws, size_t ws_size,
                              hipStream_t stream) {
  const float* x  = (const float*)d_in[0];
  const float* wq = (const float*)d_in[1];
  const float* wk = (const float*)d_in[2];
  const float* wv = (const float*)d_in[3];
  float* out = (float*)d_out;

  unsigned short* Qb  = (unsigned short*)d_ws;            // 2 MB
  unsigned short* Kb  = Qb + (size_t)SEQ * DOUT;          // 2 MB
  unsigned short* Vtb = Kb + (size_t)SEQ * DOUT;          // 2 MB (transposed)
  float* Opart = (float*)(Vtb + (size_t)SEQ * DOUT);      // 8 * 4 MB
  float* lpart = Opart + (size_t)8 * SEQ * DOUT;          // 256 KB
  // xb (12.6 MB) + Wb (0.58 MB) alias Opart: dead before attn writes it
  unsigned short* xb = (unsigned short*)Opart;
  unsigned short* Wb = xb + (size_t)XELEMS;
  if (ws_size < (size_t)(6291456 + 33554432 + 262144)) return;

  conv_kernel<<<dim3(6432), 256, 0, stream>>>(x, wq, wk, wv, xb, Wb);
  qkv_kernel<<<dim3(64, 3), 256, 0, stream>>>(xb, Wb, Qb, Kb, Vtb);
  attn_kernel<<<dim3(8, 64), 256, 0, stream>>>(Qb, Kb, Vtb, Opart, lpart);
  combine_kernel<<<dim3(1024), 256, 0, stream>>>(Opart, lpart, out);
}